// Round 9
// baseline (395.090 us; speedup 1.0000x reference)
//
#include <hip/hip_runtime.h>

// MultiHeadAttention: B=8, C=256, H=8, D=32, T=16, P=1024, F=D*T=512
//  k_wconv : W fp32 -> Wall[768][256] bf16 (chunk-swizzled by o&7)
//  k_xt    : x fp32 [b][c][n] -> Xbf [b][n][c] bf16 (chunk-swizzled by n&7)
//  k_proj2 : GEMM Wall x Xbf -> Kb,Qb,Vb [bh][p][512] bf16 (swizzled)
//  k_egemm : Pt[bh][q][p] = bf16(exp2(QK^T/S)) + fused partial Z (16 slices)
//            SWAPPED operands -> C rows=p -> 8B Pt stores, Z via shfl
//  k_zfinal: RZ[bh][p] = 1/sum(16 Zpart slices)
//  k_vt    : Vb [p][f] -> Vt [bh][f][1024] bf16 with 1/Z[p] folded in
//  k_pv    : out = Pt x Vt' -> d_out fp32
// GEMM core (gemm97): the PROVEN m97 structure — 128x128 tile, BK=64,
// 4 waves / 256 thr, single-buffered 32 KiB LDS, plain 2-barrier loop
// (sync; global_load_lds stage; sync; ds_read + 32 MFMA). Occupancy-driven:
// ~3 blocks/CU co-resident; inter-block wave overlap hides barrier drains
// (m114). No inline waitcnt / sched_barrier — compiler's fine-grained
// lgkmcnt does the intra-phase interleave.

typedef unsigned short u16;
typedef unsigned int u32;
typedef unsigned long long u64;
typedef __attribute__((ext_vector_type(8))) short bfx8;
typedef __attribute__((ext_vector_type(4))) float fx4;

constexpr float KC1 = 1.4426950408889634f / 22.627416997969522f; // log2(e)/sqrt(512)

__device__ __forceinline__ u16 f2bf(float f) {
  u32 u = __builtin_bit_cast(u32, f);
  return (u16)((u + 0x7fffu + ((u >> 16) & 1u)) >> 16);
}
__device__ __forceinline__ float bf2f(u16 v) {
  return __builtin_bit_cast(float, (u32)v << 16);
}
__device__ __forceinline__ fx4 mfma16(bfx8 a, bfx8 b, fx4 c) {
  return __builtin_amdgcn_mfma_f32_16x16x32_bf16(a, b, c, 0, 0, 0);
}
typedef __attribute__((address_space(1))) const unsigned int* as1p;
typedef __attribute__((address_space(3))) unsigned int* as3p;
__device__ __forceinline__ void gll16(const void* g, void* l) {
  __builtin_amdgcn_global_load_lds((as1p)g, (as3p)l, 16, 0, 0);
}

// ---- m97-style 128x128 GEMM core: NT K-tiles of 64, row length LK ----
// lds: 16 KiB A @0 + 16 KiB B @8192 (u16 offsets). 4 waves: wr=wv>>1 (A 64
// rows), wc=wv&1 (B 64 rows). acc[mt][nt] (non-SWAP): row = wr*64+mt*16+kg*4+j,
// col = wc*64+nt*16+l15. SWAP trades row/col sides.
template <bool SWAP, int NT, int LK>
__device__ __forceinline__ void gemm97(const u16* __restrict__ Ag,
                                       const u16* __restrict__ Bg,
                                       u16* lds, fx4 (&acc)[4][4],
                                       int wv, int lane) {
  const int l15 = lane & 15, kg = lane >> 4, l7 = lane & 7;
  const int wr = wv >> 1, wc = wv & 1;
  const int rsub = lane >> 3, csub = (lane & 7) * 8;
  bfx8 af[4][2], bf[4][2];

#pragma unroll 1
  for (int t = 0; t < NT; ++t) {
    __syncthreads();   // previous tile's readers done; LDS writable
#pragma unroll
    for (int i = 0; i < 4; ++i) {
      int r = wv * 32 + i * 8;
      gll16(Ag + (size_t)(r + rsub) * LK + t * 64 + csub, lds + r * 64);
      gll16(Bg + (size_t)(r + rsub) * LK + t * 64 + csub, lds + 8192 + r * 64);
    }
    __syncthreads();   // compiler drains vmcnt(0) here: tile landed
#pragma unroll
    for (int mt = 0; mt < 4; ++mt)
#pragma unroll
      for (int kk = 0; kk < 2; ++kk)
        af[mt][kk] = *(const bfx8*)(lds + (wr * 64 + mt * 16 + l15) * 64 +
                                    (((kk << 2) + kg) ^ l7) * 8);
#pragma unroll
    for (int nt = 0; nt < 4; ++nt)
#pragma unroll
      for (int kk = 0; kk < 2; ++kk)
        bf[nt][kk] = *(const bfx8*)(lds + 8192 + (wc * 64 + nt * 16 + l15) * 64 +
                                    (((kk << 2) + kg) ^ l7) * 8);
#pragma unroll
    for (int mt = 0; mt < 4; ++mt)
#pragma unroll
      for (int nt = 0; nt < 4; ++nt)
#pragma unroll
        for (int kk = 0; kk < 2; ++kk) {
          if constexpr (SWAP)
            acc[mt][nt] = mfma16(bf[nt][kk], af[mt][kk], acc[mt][nt]);
          else
            acc[mt][nt] = mfma16(af[mt][kk], bf[nt][kk], acc[mt][nt]);
        }
  }
}

// ---------------- W fp32 -> Wall bf16 swizzled ----------------
__global__ __launch_bounds__(256) void k_wconv(const float* __restrict__ Wk,
                                               const float* __restrict__ Wq,
                                               const float* __restrict__ Wv,
                                               u16* __restrict__ Wall) {
  int blk = blockIdx.x;          // 96 = 3 proj * 32
  int pr = blk >> 5;
  const float* src = (pr == 0) ? Wk : ((pr == 1) ? Wq : Wv);
  int oc = (blk & 31) * 8 + (threadIdx.x >> 5);
  int Cc = threadIdx.x & 31;
  const float4* s4 = (const float4*)(src + oc * 256 + Cc * 8);
  float4 a = s4[0], b = s4[1];
  alignas(16) u16 t[8] = {f2bf(a.x), f2bf(a.y), f2bf(a.z), f2bf(a.w),
                          f2bf(b.x), f2bf(b.y), f2bf(b.z), f2bf(b.w)};
  int o = pr * 256 + oc;
  int pos = (Cc & ~7) + ((Cc & 7) ^ (o & 7));
  *(uint4*)(Wall + o * 256 + pos * 8) = *(const uint4*)t;
}

// ---------------- x -> Xbf transpose/convert ----------------
__global__ __launch_bounds__(256) void k_xt(const float* __restrict__ x,
                                            u16* __restrict__ Xbf) {
  __shared__ u16 Xs[128 * 256];
  int b = blockIdx.x >> 7;
  int n0 = (blockIdx.x & 127) * 128;
  int tid = threadIdx.x;
  int ng = tid & 31, cgrp = tid >> 5;
  const float* xb = x + (size_t)b * 4194304 + n0 + ng * 4;
#pragma unroll
  for (int it = 0; it < 4; ++it) {
    int Cc = cgrp + it * 8;
    float4 v[8];
#pragma unroll
    for (int i = 0; i < 8; ++i)
      v[i] = *(const float4*)(xb + (size_t)(Cc * 8 + i) * 16384);
#pragma unroll
    for (int j = 0; j < 4; ++j) {
      int n = ng * 4 + j;
      alignas(16) u16 c8v[8];
#pragma unroll
      for (int i = 0; i < 8; ++i) c8v[i] = f2bf(((const float*)&v[i])[j]);
      int pos = (Cc & ~7) + ((Cc & 7) ^ (n & 7));
      *(uint4*)&Xs[n * 256 + pos * 8] = *(const uint4*)c8v;
    }
  }
  __syncthreads();
  u16* xo = Xbf + (size_t)b * 4194304 + (size_t)n0 * 256;
#pragma unroll
  for (int it = 0; it < 16; ++it) {
    int idx = tid + it * 256;
    int n = idx >> 5, chp = idx & 31;
    uint4 v = *(const uint4*)&Xs[n * 256 + chp * 8];
    *(uint4*)&xo[(size_t)n * 256 + chp * 8] = v;
  }
}

// ---------------- fused 3-projection GEMM ----------------
// grid 6144 (8 b x 6 mtiles x 128 ntiles), 256 thr, 128x128, NT=4.
__global__ __launch_bounds__(256, 3) void k_proj2(const u16* __restrict__ Xbf,
                                                  const u16* __restrict__ Wall,
                                                  u16* __restrict__ Kb, u16* __restrict__ Qb,
                                                  u16* __restrict__ Vb) {
  __shared__ u16 lds[16384];
  int bid = blockIdx.x;
  int vid = (bid & 7) * 768 + (bid >> 3);
  int b = vid / 768;
  int rem = vid - b * 768;
  int mtile = rem >> 7, ntile = rem & 127;
  int tid = threadIdx.x, lane = tid & 63, wv = tid >> 6;
  int l15 = lane & 15, kg = lane >> 4;
  int wr = wv >> 1, wc = wv & 1;
  const u16* Ag = Wall + mtile * 32768;
  const u16* Bg = Xbf + (size_t)b * 4194304 + (size_t)ntile * 32768;
  fx4 acc[4][4];
#pragma unroll
  for (int mt = 0; mt < 4; ++mt)
#pragma unroll
    for (int nt = 0; nt < 4; ++nt) acc[mt][nt] = (fx4)0.0f;

  gemm97<false, 4, 256>(Ag, Bg, lds, acc, wv, lane);

  int pr = mtile >> 1;
  u16* dst = (pr == 0) ? Kb : ((pr == 1) ? Qb : Vb);
  int obase = (mtile & 1) * 128 + wr * 64;
#pragma unroll
  for (int mt = 0; mt < 4; ++mt) {
    int oc = obase + mt * 16 + kg * 4;   // 0..255 within proj
    int h = oc >> 5;
    size_t bhro = (size_t)(b * 8 + h) * 524288;
#pragma unroll
    for (int nt = 0; nt < 4; ++nt) {
      int n = ntile * 128 + wc * 64 + nt * 16 + l15;
      int p = n >> 4, tt = n & 15;
      size_t ro = bhro + (size_t)p * 512;
      int p7 = p & 7;
#pragma unroll
      for (int j = 0; j < 4; ++j) {
        int f = ((oc & 31) + j) * 16 + tt;
        int ch = (f >> 3) ^ p7;
        dst[ro + ch * 8 + (f & 7)] = f2bf(acc[mt][nt][j]);
      }
    }
  }
}

// ---------------- E-GEMM + exp2 -> Pt, fused partial Z ----------------
// grid 4096 (64 bh x 8 qt x 8 pt), 256 thr, 128x128, NT=8. SWAP:
// C row = p = p0+wc*64+nt*16+kg*4+j, col = q = q0+wr*64+mt*16+l15.
__global__ __launch_bounds__(256, 3) void k_egemm(const u16* __restrict__ Qb,
                                                  const u16* __restrict__ Kb,
                                                  u16* __restrict__ Pt,
                                                  float* __restrict__ Zpart) {
  __shared__ u16 lds[16384];
  int bid = blockIdx.x;
  int vid = (bid & 7) * 512 + (bid >> 3);
  int bh = vid >> 6;
  int rem = vid & 63;
  int qt = rem >> 3, pt = rem & 7;
  int q0 = qt * 128, p0 = pt * 128;
  int tid = threadIdx.x, lane = tid & 63, wv = tid >> 6;
  int l15 = lane & 15, kg = lane >> 4;
  int wr = wv >> 1, wc = wv & 1;
  const u16* Ag = Qb + (size_t)bh * 524288 + (size_t)q0 * 512;
  const u16* Bg = Kb + (size_t)bh * 524288 + (size_t)p0 * 512;
  fx4 acc[4][4];
#pragma unroll
  for (int mt = 0; mt < 4; ++mt)
#pragma unroll
    for (int nt = 0; nt < 4; ++nt) acc[mt][nt] = (fx4)0.0f;

  gemm97<true, 8, 512>(Ag, Bg, lds, acc, wv, lane);

  size_t pbase = (size_t)bh * 1048576;
  float zac[4][4];
#pragma unroll
  for (int nt = 0; nt < 4; ++nt)
#pragma unroll
    for (int j = 0; j < 4; ++j) zac[nt][j] = 0.f;
#pragma unroll
  for (int mt = 0; mt < 4; ++mt) {
    int q = q0 + wr * 64 + mt * 16 + l15;
    size_t qrow = pbase + (size_t)q * 1024;
    int q7 = l15 & 7;
#pragma unroll
    for (int nt = 0; nt < 4; ++nt) {
      int p4 = p0 + wc * 64 + nt * 16 + kg * 4;
      alignas(8) u16 e4[4];
#pragma unroll
      for (int j = 0; j < 4; ++j) {
        float e = exp2f(acc[mt][nt][j] * KC1);
        zac[nt][j] += e;
        e4[j] = f2bf(e);
      }
      int ch = (p4 >> 3) ^ q7;
      *(u64*)(Pt + qrow + ch * 8 + (p4 & 7)) = *(const u64*)e4;
    }
  }
  // reduce z over the 16 q-lanes (l15)
#pragma unroll
  for (int nt = 0; nt < 4; ++nt)
#pragma unroll
    for (int j = 0; j < 4; ++j) {
      float v = zac[nt][j];
      v += __shfl_xor(v, 1);
      v += __shfl_xor(v, 2);
      v += __shfl_xor(v, 4);
      v += __shfl_xor(v, 8);
      zac[nt][j] = v;
    }
  if (l15 == 0) {
    size_t zb = (size_t)(qt * 2 + wr) * 65536 + (size_t)bh * 1024;
#pragma unroll
    for (int nt = 0; nt < 4; ++nt) {
      int p4 = p0 + wc * 64 + nt * 16 + kg * 4;
      float4 zv;
      zv.x = zac[nt][0]; zv.y = zac[nt][1];
      zv.z = zac[nt][2]; zv.w = zac[nt][3];
      *(float4*)&Zpart[zb + p4] = zv;
    }
  }
}

__global__ __launch_bounds__(256) void k_zfinal(const float* __restrict__ Zpart,
                                                float* __restrict__ RZ) {
  int idx = blockIdx.x * 256 + threadIdx.x; // 65536
  float s = 0.f;
#pragma unroll
  for (int k = 0; k < 16; ++k) s += Zpart[(size_t)k * 65536 + idx];
  RZ[idx] = 1.0f / s;
}

// ---------------- Vb [p][f] -> Vt [f][p] with 1/Z scale ----------------
__global__ __launch_bounds__(256) void k_vt(const u16* __restrict__ Vb,
                                            const float* __restrict__ RZ,
                                            u16* __restrict__ Vt) {
  __shared__ u16 Vl[64 * 512];
  int bh = blockIdx.x >> 4;
  int ptile = blockIdx.x & 15;
  int tid = threadIdx.x;
  const u16* src = Vb + (size_t)bh * 524288 + (size_t)ptile * 32768;
#pragma unroll
  for (int it = 0; it < 16; ++it) {
    int idx = tid + it * 256;
    int pl = idx >> 6, g = idx & 63;
    float rz = RZ[bh * 1024 + ptile * 64 + pl];
    uint4 v = *(const uint4*)&src[(size_t)pl * 512 + g * 8];
    int cf = g ^ (pl & 7);
    u32 w[4] = {v.x, v.y, v.z, v.w};
    alignas(16) u16 c8v[8];
#pragma unroll
    for (int i = 0; i < 4; ++i) {
      c8v[2 * i]     = f2bf(bf2f((u16)w[i]) * rz);
      c8v[2 * i + 1] = f2bf(bf2f((u16)(w[i] >> 16)) * rz);
    }
    *(uint4*)&Vl[pl * 512 + cf * 8] = *(const uint4*)c8v;
  }
  __syncthreads();
  u16* dst = Vt + (size_t)bh * 524288;
#pragma unroll
  for (int it = 0; it < 16; ++it) {
    int f = (tid & 63) + (it & 7) * 64;
    int pc = (tid >> 6) * 2 + (it >> 3);
    int base = pc * 8 * 512 + f;
    u32 x0 = (u32)Vl[base] | ((u32)Vl[base + 512] << 16);
    u32 x1 = (u32)Vl[base + 1024] | ((u32)Vl[base + 1536] << 16);
    u32 x2 = (u32)Vl[base + 2048] | ((u32)Vl[base + 2560] << 16);
    u32 x3 = (u32)Vl[base + 3072] | ((u32)Vl[base + 3584] << 16);
    uint4 pk; pk.x = x0; pk.y = x1; pk.z = x2; pk.w = x3;
    int col = ptile * 8 + (pc ^ (f & 7));
    *(uint4*)&dst[(size_t)f * 1024 + col * 8] = pk;
  }
}

// ---------------- PV-GEMM -> out ----------------
// grid 2048 (64 bh x 8 qt x 4 ft), 256 thr, 128x128, NT=16.
__global__ __launch_bounds__(256, 3) void k_pv(const u16* __restrict__ Pt,
                                               const u16* __restrict__ Vt,
                                               float* __restrict__ out) {
  __shared__ u16 lds[16384];
  int bid = blockIdx.x;
  int vid = (bid & 7) * 256 + (bid >> 3);
  int bh = vid >> 5;
  int rem = vid & 31;
  int qt = rem >> 2, ft = rem & 3;
  int q0 = qt * 128, f0 = ft * 128;
  int tid = threadIdx.x, lane = tid & 63, wv = tid >> 6;
  int l15 = lane & 15, kg = lane >> 4;
  int wr = wv >> 1, wc = wv & 1;
  const u16* Ag = Pt + (size_t)bh * 1048576 + (size_t)q0 * 1024;
  const u16* Bg = Vt + (size_t)bh * 524288 + (size_t)f0 * 1024;
  fx4 acc[4][4];
#pragma unroll
  for (int mt = 0; mt < 4; ++mt)
#pragma unroll
    for (int nt = 0; nt < 4; ++nt) acc[mt][nt] = (fx4)0.0f;

  gemm97<false, 16, 1024>(Ag, Bg, lds, acc, wv, lane);

#pragma unroll
  for (int mt = 0; mt < 4; ++mt) {
    int qb_ = q0 + wr * 64 + mt * 16 + kg * 4;
#pragma unroll
    for (int nt = 0; nt < 4; ++nt) {
      int f = f0 + wc * 64 + nt * 16 + l15;
      int d = f >> 4, t = f & 15;
      size_t cb = (size_t)(bh * 32 + d) * 16384 + t;
#pragma unroll
      for (int j = 0; j < 4; ++j)
        out[cb + (size_t)(qb_ + j) * 16] = acc[mt][nt][j];
    }
  }
}

extern "C" void kernel_launch(void* const* d_in, const int* in_sizes, int n_in,
                              void* d_out, int out_size, void* d_ws, size_t ws_size,
                              hipStream_t stream) {
  (void)in_sizes; (void)n_in; (void)out_size; (void)ws_size;
  const float* x  = (const float*)d_in[0];
  const float* Wk = (const float*)d_in[1];
  const float* Wq = (const float*)d_in[2];
  const float* Wv = (const float*)d_in[3];
  float* out = (float*)d_out;

  u16* Kb  = (u16*)d_ws;                  // [ 0, 64) MiB  [64 bh][1024 p][512 f]
  u16* Qb  = Kb + 33554432;               // [64,128) MiB
  u16* Vb  = Qb + 33554432;               // [128,192) MiB
  u16* Xbf = Vb + 33554432;               // [192,256) MiB [8 b][16384 n][256 c]
  u16* Pt  = Xbf;                         // [192,320) MiB (overlays dead Xbf)
  u16* Vt  = Qb;                          // [64,128) MiB  (overlays dead Qb)
  float* Zpart = (float*)(Kb + 167772160);// 320 MiB: [16][64][1024]
  float* RZ = Zpart + 1048576;            // [64][1024]
  u16* Wall = (u16*)(RZ + 65536);         // [768][256]

  k_wconv<<<96, 256, 0, stream>>>(Wk, Wq, Wv, Wall);
  k_xt<<<1024, 256, 0, stream>>>(x, Xbf);
  k_proj2<<<6144, 256, 0, stream>>>(Xbf, Wall, Kb, Qb, Vb);
  k_egemm<<<4096, 256, 0, stream>>>(Qb, Kb, Pt, Zpart);
  k_zfinal<<<256, 256, 0, stream>>>(Zpart, RZ);
  k_vt<<<1024, 256, 0, stream>>>(Vb, RZ, Vt);
  k_pv<<<2048, 256, 0, stream>>>(Pt, Vt, out);
}

// Round 10
// 359.268 us; speedup vs baseline: 1.0997x; 1.0997x over previous
//
#include <hip/hip_runtime.h>

// MultiHeadAttention: B=8, C=256, H=8, D=32, T=16, P=1024, F=D*T=512
//  k_wconv : W fp32 -> Wall[768][256] bf16 (chunk-swizzled by o&7)
//  k_projf : FUSED x->bf16 + 3-projection GEMM. Per block: stage X-tile
//            [256n][256c] bf16 ONCE in LDS (128 KiB) from fp32 x; page W
//            through a 32 KiB A-tile (single-buffered, T14 reg-prefetch);
//            loop 3 otiles x 4 K-steps; round-5 epilogue -> Kb,Qb,Vb.
//  k_egemm : Pt[bh][q][p] = bf16(exp2(QK^T/S)) + fused partial Z (8 slices)
//            round-5 gemm8 core, SWAP operands -> 8B Pt stores, shfl-Z.
//  k_zfinal: RZ[bh][p] = 1/sum(8 Zpart slices)
//  k_vt    : Vb [p][f] -> Vt [bh][f][1024] bf16 with 1/Z[p] folded in
//  k_pv    : out = Pt x Vt' (round-5 gemm8 core) -> d_out fp32

typedef unsigned short u16;
typedef unsigned int u32;
typedef unsigned long long u64;
typedef __attribute__((ext_vector_type(8))) short bfx8;
typedef __attribute__((ext_vector_type(4))) float fx4;

constexpr float KC1 = 1.4426950408889634f / 22.627416997969522f; // log2(e)/sqrt(512)

__device__ __forceinline__ u16 f2bf(float f) {
  u32 u = __builtin_bit_cast(u32, f);
  return (u16)((u + 0x7fffu + ((u >> 16) & 1u)) >> 16);
}
__device__ __forceinline__ float bf2f(u16 v) {
  return __builtin_bit_cast(float, (u32)v << 16);
}
__device__ __forceinline__ fx4 mfma16(bfx8 a, bfx8 b, fx4 c) {
  return __builtin_amdgcn_mfma_f32_16x16x32_bf16(a, b, c, 0, 0, 0);
}
typedef __attribute__((address_space(1))) const unsigned int* as1p;
typedef __attribute__((address_space(3))) unsigned int* as3p;
__device__ __forceinline__ void gll16(const void* g, void* l) {
  __builtin_amdgcn_global_load_lds((as1p)g, (as3p)l, 16, 0, 0);
}
__device__ __forceinline__ void midbar_() { __builtin_amdgcn_s_barrier(); }
__device__ __forceinline__ void pend_() {
  __builtin_amdgcn_s_barrier();
  __builtin_amdgcn_sched_barrier(0);
}
#define VMC4 do { asm volatile("s_waitcnt vmcnt(4)" ::: "memory"); \
                  __builtin_amdgcn_sched_barrier(0); } while (0)
#define VMC0 do { asm volatile("s_waitcnt vmcnt(0)" ::: "memory"); \
                  __builtin_amdgcn_sched_barrier(0); } while (0)

// ---- round-5 8-phase 256x256 GEMM core (verified), + SWAP option ----
template <bool SWAP, int NT, int LK>
__device__ __forceinline__ void gemm8(const u16* __restrict__ Ag,
                                      const u16* __restrict__ Bg,
                                      u16* lds, fx4 (&acc)[2][4][2][2],
                                      int wv, int lane) {
  const int l15 = lane & 15, kg = lane >> 4, l7 = lane & 7;
  const int wr = wv >> 2, wn = wv & 3;
  const int rsub = lane >> 3, csub = (lane & 7) * 8;
  constexpr int A0 = 0, A1 = 16384, B0 = 32768, B1 = 49152;
  bfx8 af[4][2], bf[2][2][2];

  auto stg = [&](const u16* g, int ldsoff, int tile, int half) {
    const u16* gp = g + (size_t)(half * 128 + wv * 16 + rsub) * LK + tile * 64 + csub;
    u16* lp = lds + ldsoff + half * 8192 + wv * 1024;
    gll16(gp, lp);
    gll16(gp + (size_t)8 * LK, lp + 512);
  };
  auto LA = [&](int boff, int mh) {
    const u16* base = lds + boff + mh * 8192 + wr * 4096;
#pragma unroll
    for (int mt = 0; mt < 4; ++mt)
#pragma unroll
      for (int kk = 0; kk < 2; ++kk)
        af[mt][kk] = *(const bfx8*)(base + (mt * 16 + l15) * 64 + (((kk << 2) + kg) ^ l7) * 8);
  };
  auto LB = [&](int boff, int nh) {
    const u16* base = lds + boff + nh * 8192 + wn * 2048;
#pragma unroll
    for (int nt = 0; nt < 2; ++nt)
#pragma unroll
      for (int kk = 0; kk < 2; ++kk)
        bf[nh][nt][kk] = *(const bfx8*)(base + (nt * 16 + l15) * 64 + (((kk << 2) + kg) ^ l7) * 8);
  };
  auto MM = [&](int mh, int nh) {
    __builtin_amdgcn_s_setprio(1);
#pragma unroll
    for (int mt = 0; mt < 4; ++mt)
#pragma unroll
      for (int nt = 0; nt < 2; ++nt)
#pragma unroll
        for (int kk = 0; kk < 2; ++kk) {
          if constexpr (SWAP)
            acc[mh][mt][nh][nt] = mfma16(bf[nh][nt][kk], af[mt][kk], acc[mh][mt][nh][nt]);
          else
            acc[mh][mt][nh][nt] = mfma16(af[mt][kk], bf[nh][nt][kk], acc[mh][mt][nh][nt]);
        }
    __builtin_amdgcn_s_setprio(0);
  };

  stg(Ag, A0, 0, 0); stg(Ag, A0, 0, 1);
  stg(Bg, B0, 0, 0); stg(Bg, B0, 0, 1);
  stg(Ag, A1, 1, 0); stg(Bg, B1, 1, 1);
  VMC4;
  pend_();

  constexpr int NI = NT / 2;
#pragma unroll 1
  for (int i = 0; i < NI; ++i) {
    const int t = 2 * i;
    const bool more = (i + 1 < NI);
    LA(A0, 0); LB(B0, 0);
    stg(Ag, A1, t + 1, 1);
    midbar_(); MM(0, 0); pend_();
    LB(B0, 1);
    stg(Bg, B1, t + 1, 0);
    midbar_(); MM(0, 1); pend_();
    LA(A0, 1);
    if (more) stg(Ag, A0, t + 2, 0);
    midbar_(); MM(1, 1); pend_();
    if (more) stg(Bg, B0, t + 2, 1);
    midbar_(); MM(1, 0);
    if (more) { VMC4; } else { VMC0; }
    pend_();
    LA(A1, 0); LB(B1, 0);
    if (more) stg(Ag, A0, t + 2, 1);
    midbar_(); MM(0, 0); pend_();
    LB(B1, 1);
    if (more) stg(Bg, B0, t + 2, 0);
    midbar_(); MM(0, 1); pend_();
    LA(A1, 1);
    if (more) stg(Ag, A1, t + 3, 0);
    midbar_(); MM(1, 1); pend_();
    if (more) stg(Bg, B1, t + 3, 1);
    midbar_(); MM(1, 0);
    if (more) { VMC4; }
    pend_();
  }
}

// ---------------- W fp32 -> Wall bf16 swizzled ----------------
__global__ __launch_bounds__(256) void k_wconv(const float* __restrict__ Wk,
                                               const float* __restrict__ Wq,
                                               const float* __restrict__ Wv,
                                               u16* __restrict__ Wall) {
  int blk = blockIdx.x;          // 96 = 3 proj * 32
  int pr = blk >> 5;
  const float* src = (pr == 0) ? Wk : ((pr == 1) ? Wq : Wv);
  int oc = (blk & 31) * 8 + (threadIdx.x >> 5);
  int Cc = threadIdx.x & 31;
  const float4* s4 = (const float4*)(src + oc * 256 + Cc * 8);
  float4 a = s4[0], b = s4[1];
  alignas(16) u16 t[8] = {f2bf(a.x), f2bf(a.y), f2bf(a.z), f2bf(a.w),
                          f2bf(b.x), f2bf(b.y), f2bf(b.z), f2bf(b.w)};
  int o = pr * 256 + oc;
  int pos = (Cc & ~7) + ((Cc & 7) ^ (o & 7));
  *(uint4*)(Wall + o * 256 + pos * 8) = *(const uint4*)t;
}

// ---------------- FUSED x-convert + 3-projection GEMM ----------------
// grid 512 (8 b x 64 ntiles of 256 n), 512 thr, 160 KiB LDS.
__global__ __launch_bounds__(512, 1) void k_projf(const float* __restrict__ x,
                                                  const u16* __restrict__ Wall,
                                                  u16* __restrict__ Kb, u16* __restrict__ Qb,
                                                  u16* __restrict__ Vb) {
  __shared__ u16 Xs[65536];   // [256 n][256 c] bf16, chunk^=(n&7) per 8-group
  __shared__ u16 Aw[16384];   // [256 o][64 c] for current K-step
  int bid = blockIdx.x;
  int vid = (bid & 7) * 64 + (bid >> 3);
  int b = vid >> 6, ntile = vid & 63;
  int n0 = ntile * 256;
  int tid = threadIdx.x, lane = tid & 63, wv = tid >> 6;
  int l15 = lane & 15, kg = lane >> 4, l7 = lane & 7;
  int wr = wv >> 2, wn = wv & 3;
  int rs8 = lane >> 3, c8o = (lane & 7) * 8;
  bfx8 areg[4];

  auto issueA = [&](int ot, int ks) {
    const u16* Ao = Wall + ot * 65536;
#pragma unroll
    for (int i = 0; i < 4; ++i) {
      int r = wv * 32 + i * 8;
      areg[i] = *(const bfx8*)(Ao + (size_t)(r + rs8) * 256 + ks * 64 + c8o);
    }
  };
  auto writeA = [&]() {
#pragma unroll
    for (int i = 0; i < 4; ++i) {
      int r = wv * 32 + i * 8;
      *(bfx8*)&Aw[r * 64 + lane * 8] = areg[i];
    }
  };

  issueA(0, 0);   // in flight during X staging

  { // stage X: fp32 [c][n] -> bf16 [n][c] swizzled (k_xt pattern, 512 thr)
    int ng = tid & 63, cgrp = tid >> 6;
    const float* xb = x + (size_t)b * 4194304 + n0 + ng * 4;
#pragma unroll
    for (int it = 0; it < 4; ++it) {
      int Cc = cgrp + it * 8;     // 0..31
      float4 v[8];
#pragma unroll
      for (int i = 0; i < 8; ++i)
        v[i] = *(const float4*)(xb + (size_t)(Cc * 8 + i) * 16384);
#pragma unroll
      for (int j = 0; j < 4; ++j) {
        int n = ng * 4 + j;
        alignas(16) u16 c8v[8];
#pragma unroll
        for (int i = 0; i < 8; ++i) c8v[i] = f2bf(((const float*)&v[i])[j]);
        int pos = (Cc & ~7) + ((Cc & 7) ^ (n & 7));
        *(uint4*)&Xs[n * 256 + pos * 8] = *(const uint4*)c8v;
      }
    }
  }
  __syncthreads();

  bfx8 af[4][2], bf[2][2][2];
  fx4 acc[2][4][2][2];

  auto LAx = [&](int mh) {
#pragma unroll
    for (int mt = 0; mt < 4; ++mt) {
      int row = mh * 128 + wr * 64 + mt * 16 + l15;
#pragma unroll
      for (int kk = 0; kk < 2; ++kk)
        af[mt][kk] = *(const bfx8*)&Aw[row * 64 + (((kk << 2) + kg) ^ l7) * 8];
    }
  };
  auto LBx = [&](int nh, int ks) {
#pragma unroll
    for (int nt = 0; nt < 2; ++nt) {
      int n = nh * 128 + wn * 32 + nt * 16 + l15;
#pragma unroll
      for (int kk = 0; kk < 2; ++kk)
        bf[nh][nt][kk] = *(const bfx8*)&Xs[n * 256 + (ks * 8 + (((kk << 2) + kg) ^ l7)) * 8];
    }
  };
  auto MMx = [&](int mh, int nh) {
    __builtin_amdgcn_s_setprio(1);
#pragma unroll
    for (int mt = 0; mt < 4; ++mt)
#pragma unroll
      for (int nt = 0; nt < 2; ++nt)
#pragma unroll
        for (int kk = 0; kk < 2; ++kk)
          acc[mh][mt][nh][nt] = mfma16(af[mt][kk], bf[nh][nt][kk], acc[mh][mt][nh][nt]);
    __builtin_amdgcn_s_setprio(0);
  };

#pragma unroll 1
  for (int ot = 0; ot < 3; ++ot) {
#pragma unroll
    for (int mh = 0; mh < 2; ++mh)
#pragma unroll
      for (int mt = 0; mt < 4; ++mt)
#pragma unroll
        for (int nh = 0; nh < 2; ++nh)
#pragma unroll
          for (int nt = 0; nt < 2; ++nt) acc[mh][mt][nh][nt] = (fx4)0.0f;

#pragma unroll 1
    for (int ks = 0; ks < 4; ++ks) {
      writeA();                              // waits areg (data dep)
      if (!(ot == 2 && ks == 3)) {
        int not_ = (ks == 3) ? ot + 1 : ot;
        int nks = (ks == 3) ? 0 : ks + 1;
        issueA(not_, nks);                   // T14: issue early
      }
      __syncthreads();                       // Aw visible
      LAx(0); LBx(0, ks);
      MMx(0, 0);
      LBx(1, ks);
      MMx(0, 1);
      LAx(1);
      MMx(1, 1);
      MMx(1, 0);
      __syncthreads();                       // all reads of Aw done
    }
    // epilogue (round-5 proj algebra), no LDS use
    u16* dst = (ot == 0) ? Kb : ((ot == 1) ? Qb : Vb);
#pragma unroll
    for (int mh = 0; mh < 2; ++mh)
#pragma unroll
      for (int mt = 0; mt < 4; ++mt) {
        int o = mh * 128 + wr * 64 + mt * 16 + kg * 4;
        int h = o >> 5;
        size_t bhro = (size_t)(b * 8 + h) * 524288;
#pragma unroll
        for (int nh = 0; nh < 2; ++nh)
#pragma unroll
          for (int nt = 0; nt < 2; ++nt) {
            int p = ntile * 16 + nh * 8 + wn * 2 + nt;
            size_t ro = bhro + (size_t)p * 512;
            int p7 = p & 7;
#pragma unroll
            for (int j = 0; j < 4; ++j) {
              int f = ((o & 31) + j) * 16 + l15;
              int ch = (f >> 3) ^ p7;
              dst[ro + ch * 8 + (f & 7)] = f2bf(acc[mh][mt][nh][nt][j]);
            }
          }
      }
  }
}

// ---------------- E-GEMM + exp2 -> Pt, fused partial Z ----------------
// grid 1024 (bh x 4 qt x 4 pt), 512 thr, 256x256, NT=8. SWAP:
// row = p = p0+nh*128+wn*32+nt*16+kg*4+j, col = q = q0+mh*128+wr*64+mt*16+l15.
__global__ __launch_bounds__(512) void k_egemm(const u16* __restrict__ Qb,
                                               const u16* __restrict__ Kb,
                                               u16* __restrict__ Pt,
                                               float* __restrict__ Zpart) {
  __shared__ u16 lds[65536];
  int bid = blockIdx.x;
  int vid = (bid & 7) * 128 + (bid >> 3);
  int bh = vid >> 4, qt = (vid >> 2) & 3, pt = vid & 3;
  int q0 = qt * 256, p0 = pt * 256;
  int tid = threadIdx.x, lane = tid & 63, wv = tid >> 6;
  int l15 = lane & 15, kg = lane >> 4;
  int wr = wv >> 2, wn = wv & 3;
  const u16* Ag = Qb + (size_t)bh * 524288 + (size_t)q0 * 512;
  const u16* Bg = Kb + (size_t)bh * 524288 + (size_t)p0 * 512;
  fx4 acc[2][4][2][2];
#pragma unroll
  for (int mh = 0; mh < 2; ++mh)
#pragma unroll
    for (int mt = 0; mt < 4; ++mt)
#pragma unroll
      for (int nh = 0; nh < 2; ++nh)
#pragma unroll
        for (int nt = 0; nt < 2; ++nt) acc[mh][mt][nh][nt] = (fx4)0.0f;

  gemm8<true, 8, 512>(Ag, Bg, lds, acc, wv, lane);

  size_t pbase = (size_t)bh * 1048576;
  float zac[2][2][4];
#pragma unroll
  for (int nh = 0; nh < 2; ++nh)
#pragma unroll
    for (int nt = 0; nt < 2; ++nt)
#pragma unroll
      for (int j = 0; j < 4; ++j) zac[nh][nt][j] = 0.f;
#pragma unroll
  for (int mh = 0; mh < 2; ++mh)
#pragma unroll
    for (int mt = 0; mt < 4; ++mt) {
      int q = q0 + mh * 128 + wr * 64 + mt * 16 + l15;
      size_t qrow = pbase + (size_t)q * 1024;
      int q7 = l15 & 7;
#pragma unroll
      for (int nh = 0; nh < 2; ++nh)
#pragma unroll
        for (int nt = 0; nt < 2; ++nt) {
          int p4 = p0 + nh * 128 + wn * 32 + nt * 16 + kg * 4;
          alignas(8) u16 e4[4];
#pragma unroll
          for (int j = 0; j < 4; ++j) {
            float e = exp2f(acc[mh][mt][nh][nt][j] * KC1);
            zac[nh][nt][j] += e;
            e4[j] = f2bf(e);
          }
          int ch = (p4 >> 3) ^ q7;
          *(u64*)(Pt + qrow + ch * 8 + (p4 & 7)) = *(const u64*)e4;
        }
    }
#pragma unroll
  for (int nh = 0; nh < 2; ++nh)
#pragma unroll
    for (int nt = 0; nt < 2; ++nt)
#pragma unroll
      for (int j = 0; j < 4; ++j) {
        float v = zac[nh][nt][j];
        v += __shfl_xor(v, 1);
        v += __shfl_xor(v, 2);
        v += __shfl_xor(v, 4);
        v += __shfl_xor(v, 8);
        zac[nh][nt][j] = v;
      }
  if (l15 == 0) {
    size_t zb = (size_t)(qt * 2 + wr) * 65536 + (size_t)bh * 1024;
#pragma unroll
    for (int nh = 0; nh < 2; ++nh)
#pragma unroll
      for (int nt = 0; nt < 2; ++nt) {
        int p4 = p0 + nh * 128 + wn * 32 + nt * 16 + kg * 4;
        float4 zv;
        zv.x = zac[nh][nt][0]; zv.y = zac[nh][nt][1];
        zv.z = zac[nh][nt][2]; zv.w = zac[nh][nt][3];
        *(float4*)&Zpart[zb + p4] = zv;
      }
  }
}

__global__ __launch_bounds__(256) void k_zfinal(const float* __restrict__ Zpart,
                                                float* __restrict__ RZ) {
  int idx = blockIdx.x * 256 + threadIdx.x; // 65536
  float s = 0.f;
#pragma unroll
  for (int k = 0; k < 8; ++k) s += Zpart[(size_t)k * 65536 + idx];
  RZ[idx] = 1.0f / s;
}

// ---------------- Vb [p][f] -> Vt [f][p] with 1/Z scale ----------------
__global__ __launch_bounds__(256) void k_vt(const u16* __restrict__ Vb,
                                            const float* __restrict__ RZ,
                                            u16* __restrict__ Vt) {
  __shared__ u16 Vl[64 * 512];
  int bh = blockIdx.x >> 4;
  int ptile = blockIdx.x & 15;
  int tid = threadIdx.x;
  const u16* src = Vb + (size_t)bh * 524288 + (size_t)ptile * 32768;
#pragma unroll
  for (int it = 0; it < 16; ++it) {
    int idx = tid + it * 256;
    int pl = idx >> 6, g = idx & 63;
    float rz = RZ[bh * 1024 + ptile * 64 + pl];
    uint4 v = *(const uint4*)&src[(size_t)pl * 512 + g * 8];
    int cf = g ^ (pl & 7);
    u32 w[4] = {v.x, v.y, v.z, v.w};
    alignas(16) u16 c8v[8];
#pragma unroll
    for (int i = 0; i < 4; ++i) {
      c8v[2 * i]     = f2bf(bf2f((u16)w[i]) * rz);
      c8v[2 * i + 1] = f2bf(bf2f((u16)(w[i] >> 16)) * rz);
    }
    *(uint4*)&Vl[pl * 512 + cf * 8] = *(const uint4*)c8v;
  }
  __syncthreads();
  u16* dst = Vt + (size_t)bh * 524288;
#pragma unroll
  for (int it = 0; it < 16; ++it) {
    int f = (tid & 63) + (it & 7) * 64;
    int pc = (tid >> 6) * 2 + (it >> 3);
    int base = pc * 8 * 512 + f;
    u32 x0 = (u32)Vl[base] | ((u32)Vl[base + 512] << 16);
    u32 x1 = (u32)Vl[base + 1024] | ((u32)Vl[base + 1536] << 16);
    u32 x2 = (u32)Vl[base + 2048] | ((u32)Vl[base + 2560] << 16);
    u32 x3 = (u32)Vl[base + 3072] | ((u32)Vl[base + 3584] << 16);
    uint4 pk; pk.x = x0; pk.y = x1; pk.z = x2; pk.w = x3;
    int col = ptile * 8 + (pc ^ (f & 7));
    *(uint4*)&dst[(size_t)f * 1024 + col * 8] = pk;
  }
}

// ---------------- PV-GEMM -> out ----------------
// grid 512 (bh x 8 tiles), 512 thr, 256x256, NT=16.
__global__ __launch_bounds__(512) void k_pv(const u16* __restrict__ Pt,
                                            const u16* __restrict__ Vt,
                                            float* __restrict__ out) {
  __shared__ u16 lds[65536];
  int bid = blockIdx.x;
  int vid = (bid & 7) * 64 + (bid >> 3);
  int bh = vid >> 3, tile = vid & 7;
  int q0 = (tile >> 1) * 256, f0 = (tile & 1) * 256;
  int tid = threadIdx.x, lane = tid & 63, wv = tid >> 6;
  int l15 = lane & 15, kg = lane >> 4;
  int wr = wv >> 2, wn = wv & 3;
  const u16* Ag = Pt + (size_t)bh * 1048576 + (size_t)q0 * 1024;
  const u16* Bg = Vt + (size_t)bh * 524288 + (size_t)f0 * 1024;
  fx4 acc[2][4][2][2];
#pragma unroll
  for (int mh = 0; mh < 2; ++mh)
#pragma unroll
    for (int mt = 0; mt < 4; ++mt)
#pragma unroll
      for (int nh = 0; nh < 2; ++nh)
#pragma unroll
        for (int nt = 0; nt < 2; ++nt) acc[mh][mt][nh][nt] = (fx4)0.0f;

  gemm8<false, 16, 1024>(Ag, Bg, lds, acc, wv, lane);

#pragma unroll
  for (int mh = 0; mh < 2; ++mh)
#pragma unroll
    for (int mt = 0; mt < 4; ++mt) {
      int qb_ = q0 + mh * 128 + wr * 64 + mt * 16 + kg * 4;
#pragma unroll
      for (int nh = 0; nh < 2; ++nh)
#pragma unroll
        for (int nt = 0; nt < 2; ++nt) {
          int f = f0 + nh * 128 + wn * 32 + nt * 16 + l15;
          int d = f >> 4, t = f & 15;
          size_t cb = (size_t)(bh * 32 + d) * 16384 + t;
#pragma unroll
          for (int j = 0; j < 4; ++j)
            out[cb + (size_t)(qb_ + j) * 16] = acc[mh][mt][nh][nt][j];
        }
    }
}

extern "C" void kernel_launch(void* const* d_in, const int* in_sizes, int n_in,
                              void* d_out, int out_size, void* d_ws, size_t ws_size,
                              hipStream_t stream) {
  (void)in_sizes; (void)n_in; (void)out_size; (void)ws_size;
  const float* x  = (const float*)d_in[0];
  const float* Wk = (const float*)d_in[1];
  const float* Wq = (const float*)d_in[2];
  const float* Wv = (const float*)d_in[3];
  float* out = (float*)d_out;

  u16* Kb  = (u16*)d_ws;                  // [ 0, 64) MiB  [64 bh][1024 p][512 f]
  u16* Qb  = Kb + 33554432;               // [64,128) MiB
  u16* Vb  = Qb + 33554432;               // [128,192) MiB
  u16* Pt  = Vb + 33554432;               // [192,320) MiB [64 bh][1024 q][1024 p]
  u16* Vt  = Qb;                          // [64,128) MiB  (overlays dead Qb)
  float* Zpart = (float*)(Kb + 167772160);// 320 MiB: [8][64][1024]
  float* RZ = Zpart + 524288;             // [64][1024]
  u16* Wall = (u16*)(RZ + 65536);         // [768][256]

  k_wconv<<<96, 256, 0, stream>>>(Wk, Wq, Wv, Wall);
  k_projf<<<512, 512, 0, stream>>>(x, Wall, Kb, Qb, Vb);
  k_egemm<<<1024, 512, 0, stream>>>(Qb, Kb, Pt, Zpart);
  k_zfinal<<<256, 256, 0, stream>>>(Zpart, RZ);
  k_vt<<<1024, 256, 0, stream>>>(Vb, RZ, Vt);
  k_pv<<<512, 512, 0, stream>>>(Pt, Vt, out);
}

// Round 11
// 348.400 us; speedup vs baseline: 1.1340x; 1.0312x over previous
//
#include <hip/hip_runtime.h>

// MultiHeadAttention: B=8, C=256, H=8, D=32, T=16, P=1024, F=D*T=512
//  k_wconv : W fp32 -> Wall[768][256] bf16 (chunk-swizzled by o&7)
//  k_xt    : x fp32 [b][c][n] -> Xbf [b][n][c] bf16 (chunk-swizzled by n&7)
//  k_proj2 : GEMM Wall x Xbf -> Kb,Qb,Vb [bh][p][512] bf16 (swizzled).
//            8-phase gemm8 core, SWAP operands -> j runs over t=n&15 ->
//            8B stores (32/thread instead of 128 scalar u16).
//  k_egemm : Pt[bh][q][p] = bf16(exp2(QK^T/S)) + fused partial Z (8 slices)
//            SWAP -> 8B Pt stores, shfl-Z. (round-10, verified)
//  k_zfinal: RZ[bh][p] = 1/sum(8 Zpart slices)
//  k_vt    : Vb [p][f] -> Vt [bh][f][1024] bf16 with 1/Z[p] folded in
//  k_pv    : out = Pt x Vt'. SWAP -> j runs over t=f&15 -> float4 out stores
//            (32/thread, full-cacheline coalesced across kg groups).

typedef unsigned short u16;
typedef unsigned int u32;
typedef unsigned long long u64;
typedef __attribute__((ext_vector_type(8))) short bfx8;
typedef __attribute__((ext_vector_type(4))) float fx4;

constexpr float KC1 = 1.4426950408889634f / 22.627416997969522f; // log2(e)/sqrt(512)

__device__ __forceinline__ u16 f2bf(float f) {
  u32 u = __builtin_bit_cast(u32, f);
  return (u16)((u + 0x7fffu + ((u >> 16) & 1u)) >> 16);
}
__device__ __forceinline__ float bf2f(u16 v) {
  return __builtin_bit_cast(float, (u32)v << 16);
}
__device__ __forceinline__ fx4 mfma16(bfx8 a, bfx8 b, fx4 c) {
  return __builtin_amdgcn_mfma_f32_16x16x32_bf16(a, b, c, 0, 0, 0);
}
typedef __attribute__((address_space(1))) const unsigned int* as1p;
typedef __attribute__((address_space(3))) unsigned int* as3p;
__device__ __forceinline__ void gll16(const void* g, void* l) {
  __builtin_amdgcn_global_load_lds((as1p)g, (as3p)l, 16, 0, 0);
}
__device__ __forceinline__ void midbar_() { __builtin_amdgcn_s_barrier(); }
__device__ __forceinline__ void pend_() {
  __builtin_amdgcn_s_barrier();
  __builtin_amdgcn_sched_barrier(0);
}
#define VMC4 do { asm volatile("s_waitcnt vmcnt(4)" ::: "memory"); \
                  __builtin_amdgcn_sched_barrier(0); } while (0)
#define VMC0 do { asm volatile("s_waitcnt vmcnt(0)" ::: "memory"); \
                  __builtin_amdgcn_sched_barrier(0); } while (0)

// ---- round-5 8-phase 256x256 GEMM core (verified), + SWAP option ----
// SWAP epilogue convention (verified via round-10 egemm):
//   A-side value = mh*128 + wr*64 + mt*16 + l15  (carries l15)
//   B-side value = nh*128 + wn*32 + nt*16 + kg*4 + j  (carries j)
template <bool SWAP, int NT, int LK>
__device__ __forceinline__ void gemm8(const u16* __restrict__ Ag,
                                      const u16* __restrict__ Bg,
                                      u16* lds, fx4 (&acc)[2][4][2][2],
                                      int wv, int lane) {
  const int l15 = lane & 15, kg = lane >> 4, l7 = lane & 7;
  const int wr = wv >> 2, wn = wv & 3;
  const int rsub = lane >> 3, csub = (lane & 7) * 8;
  constexpr int A0 = 0, A1 = 16384, B0 = 32768, B1 = 49152;
  bfx8 af[4][2], bf[2][2][2];

  auto stg = [&](const u16* g, int ldsoff, int tile, int half) {
    const u16* gp = g + (size_t)(half * 128 + wv * 16 + rsub) * LK + tile * 64 + csub;
    u16* lp = lds + ldsoff + half * 8192 + wv * 1024;
    gll16(gp, lp);
    gll16(gp + (size_t)8 * LK, lp + 512);
  };
  auto LA = [&](int boff, int mh) {
    const u16* base = lds + boff + mh * 8192 + wr * 4096;
#pragma unroll
    for (int mt = 0; mt < 4; ++mt)
#pragma unroll
      for (int kk = 0; kk < 2; ++kk)
        af[mt][kk] = *(const bfx8*)(base + (mt * 16 + l15) * 64 + (((kk << 2) + kg) ^ l7) * 8);
  };
  auto LB = [&](int boff, int nh) {
    const u16* base = lds + boff + nh * 8192 + wn * 2048;
#pragma unroll
    for (int nt = 0; nt < 2; ++nt)
#pragma unroll
      for (int kk = 0; kk < 2; ++kk)
        bf[nh][nt][kk] = *(const bfx8*)(base + (nt * 16 + l15) * 64 + (((kk << 2) + kg) ^ l7) * 8);
  };
  auto MM = [&](int mh, int nh) {
    __builtin_amdgcn_s_setprio(1);
#pragma unroll
    for (int mt = 0; mt < 4; ++mt)
#pragma unroll
      for (int nt = 0; nt < 2; ++nt)
#pragma unroll
        for (int kk = 0; kk < 2; ++kk) {
          if constexpr (SWAP)
            acc[mh][mt][nh][nt] = mfma16(bf[nh][nt][kk], af[mt][kk], acc[mh][mt][nh][nt]);
          else
            acc[mh][mt][nh][nt] = mfma16(af[mt][kk], bf[nh][nt][kk], acc[mh][mt][nh][nt]);
        }
    __builtin_amdgcn_s_setprio(0);
  };

  stg(Ag, A0, 0, 0); stg(Ag, A0, 0, 1);
  stg(Bg, B0, 0, 0); stg(Bg, B0, 0, 1);
  stg(Ag, A1, 1, 0); stg(Bg, B1, 1, 1);
  VMC4;
  pend_();

  constexpr int NI = NT / 2;
#pragma unroll 1
  for (int i = 0; i < NI; ++i) {
    const int t = 2 * i;
    const bool more = (i + 1 < NI);
    LA(A0, 0); LB(B0, 0);
    stg(Ag, A1, t + 1, 1);
    midbar_(); MM(0, 0); pend_();
    LB(B0, 1);
    stg(Bg, B1, t + 1, 0);
    midbar_(); MM(0, 1); pend_();
    LA(A0, 1);
    if (more) stg(Ag, A0, t + 2, 0);
    midbar_(); MM(1, 1); pend_();
    if (more) stg(Bg, B0, t + 2, 1);
    midbar_(); MM(1, 0);
    if (more) { VMC4; } else { VMC0; }
    pend_();
    LA(A1, 0); LB(B1, 0);
    if (more) stg(Ag, A0, t + 2, 1);
    midbar_(); MM(0, 0); pend_();
    LB(B1, 1);
    if (more) stg(Bg, B0, t + 2, 0);
    midbar_(); MM(0, 1); pend_();
    LA(A1, 1);
    if (more) stg(Ag, A1, t + 3, 0);
    midbar_(); MM(1, 1); pend_();
    if (more) stg(Bg, B1, t + 3, 1);
    midbar_(); MM(1, 0);
    if (more) { VMC4; }
    pend_();
  }
}

// ---------------- W fp32 -> Wall bf16 swizzled ----------------
__global__ __launch_bounds__(256) void k_wconv(const float* __restrict__ Wk,
                                               const float* __restrict__ Wq,
                                               const float* __restrict__ Wv,
                                               u16* __restrict__ Wall) {
  int blk = blockIdx.x;          // 96 = 3 proj * 32
  int pr = blk >> 5;
  const float* src = (pr == 0) ? Wk : ((pr == 1) ? Wq : Wv);
  int oc = (blk & 31) * 8 + (threadIdx.x >> 5);
  int Cc = threadIdx.x & 31;
  const float4* s4 = (const float4*)(src + oc * 256 + Cc * 8);
  float4 a = s4[0], b = s4[1];
  alignas(16) u16 t[8] = {f2bf(a.x), f2bf(a.y), f2bf(a.z), f2bf(a.w),
                          f2bf(b.x), f2bf(b.y), f2bf(b.z), f2bf(b.w)};
  int o = pr * 256 + oc;
  int pos = (Cc & ~7) + ((Cc & 7) ^ (o & 7));
  *(uint4*)(Wall + o * 256 + pos * 8) = *(const uint4*)t;
}

// ---------------- x -> Xbf transpose/convert (round-5, verified) ----------------
__global__ __launch_bounds__(256) void k_xt(const float* __restrict__ x,
                                            u16* __restrict__ Xbf) {
  __shared__ u16 Xs[128 * 256];
  int b = blockIdx.x >> 7;
  int n0 = (blockIdx.x & 127) * 128;
  int tid = threadIdx.x;
  int ng = tid & 31, cgrp = tid >> 5;
  const float* xb = x + (size_t)b * 4194304 + n0 + ng * 4;
#pragma unroll
  for (int it = 0; it < 4; ++it) {
    int Cc = cgrp + it * 8;
    float4 v[8];
#pragma unroll
    for (int i = 0; i < 8; ++i)
      v[i] = *(const float4*)(xb + (size_t)(Cc * 8 + i) * 16384);
#pragma unroll
    for (int j = 0; j < 4; ++j) {
      int n = ng * 4 + j;
      alignas(16) u16 c8v[8];
#pragma unroll
      for (int i = 0; i < 8; ++i) c8v[i] = f2bf(((const float*)&v[i])[j]);
      int pos = (Cc & ~7) + ((Cc & 7) ^ (n & 7));
      *(uint4*)&Xs[n * 256 + pos * 8] = *(const uint4*)c8v;
    }
  }
  __syncthreads();
  u16* xo = Xbf + (size_t)b * 4194304 + (size_t)n0 * 256;
#pragma unroll
  for (int it = 0; it < 16; ++it) {
    int idx = tid + it * 256;
    int n = idx >> 5, chp = idx & 31;
    uint4 v = *(const uint4*)&Xs[n * 256 + chp * 8];
    *(uint4*)&xo[(size_t)n * 256 + chp * 8] = v;
  }
}

// ---------------- fused 3-projection GEMM (SWAP, 8B stores) ----------------
// grid 1536 (=512 n-groups x 3 otiles), 512 thr, 256(o) x 256(n), NT=4.
__global__ __launch_bounds__(512) void k_proj2(const u16* __restrict__ Xbf,
                                               const u16* __restrict__ Wall,
                                               u16* __restrict__ Kb, u16* __restrict__ Qb,
                                               u16* __restrict__ Vb) {
  __shared__ u16 lds[65536];
  int bid = blockIdx.x;
  int vid = (bid & 7) * 192 + (bid >> 3);
  int nidx = vid / 3;
  int otile = vid - nidx * 3;
  int b = nidx >> 6, ntile = nidx & 63;
  int tid = threadIdx.x, lane = tid & 63, wv = tid >> 6;
  int l15 = lane & 15, kg = lane >> 4;
  int wr = wv >> 2, wn = wv & 3;
  const u16* Ag = Wall + otile * 65536;
  const u16* Bg = Xbf + (size_t)b * 4194304 + (size_t)ntile * 65536;
  fx4 acc[2][4][2][2];
#pragma unroll
  for (int mh = 0; mh < 2; ++mh)
#pragma unroll
    for (int mt = 0; mt < 4; ++mt)
#pragma unroll
      for (int nh = 0; nh < 2; ++nh)
#pragma unroll
        for (int nt = 0; nt < 2; ++nt) acc[mh][mt][nh][nt] = (fx4)0.0f;

  gemm8<true, 4, 256>(Ag, Bg, lds, acc, wv, lane);

  u16* dst = (otile == 0) ? Kb : ((otile == 1) ? Qb : Vb);
#pragma unroll
  for (int mh = 0; mh < 2; ++mh)
#pragma unroll
    for (int mt = 0; mt < 4; ++mt) {
      int o = mh * 128 + wr * 64 + mt * 16 + l15;   // A-side: carries l15
      int h = o >> 5;
      int d = o & 31;
      size_t bhro = (size_t)(b * 8 + h) * 524288;
      int f0 = d * 16 + kg * 4;                      // t = kg*4 + j
      int f7 = f0 & 7;                               // (kg&1)*4
      int fc = f0 >> 3;
#pragma unroll
      for (int nh = 0; nh < 2; ++nh)
#pragma unroll
        for (int nt = 0; nt < 2; ++nt) {
          int p = ntile * 16 + nh * 8 + wn * 2 + nt; // B-side p (j is t)
          alignas(8) u16 e4[4];
#pragma unroll
          for (int j = 0; j < 4; ++j) e4[j] = f2bf(acc[mh][mt][nh][nt][j]);
          int ch = fc ^ (p & 7);
          *(u64*)(dst + bhro + (size_t)p * 512 + ch * 8 + f7) = *(const u64*)e4;
        }
    }
}

// ---------------- E-GEMM + exp2 -> Pt, fused partial Z (round-10) ----------------
// grid 1024 (bh x 4 qt x 4 pt), 512 thr, 256x256, NT=8. SWAP:
// row = p = p0+nh*128+wn*32+nt*16+kg*4+j, col = q = q0+mh*128+wr*64+mt*16+l15.
__global__ __launch_bounds__(512) void k_egemm(const u16* __restrict__ Qb,
                                               const u16* __restrict__ Kb,
                                               u16* __restrict__ Pt,
                                               float* __restrict__ Zpart) {
  __shared__ u16 lds[65536];
  int bid = blockIdx.x;
  int vid = (bid & 7) * 128 + (bid >> 3);
  int bh = vid >> 4, qt = (vid >> 2) & 3, pt = vid & 3;
  int q0 = qt * 256, p0 = pt * 256;
  int tid = threadIdx.x, lane = tid & 63, wv = tid >> 6;
  int l15 = lane & 15, kg = lane >> 4;
  int wr = wv >> 2, wn = wv & 3;
  const u16* Ag = Qb + (size_t)bh * 524288 + (size_t)q0 * 512;
  const u16* Bg = Kb + (size_t)bh * 524288 + (size_t)p0 * 512;
  fx4 acc[2][4][2][2];
#pragma unroll
  for (int mh = 0; mh < 2; ++mh)
#pragma unroll
    for (int mt = 0; mt < 4; ++mt)
#pragma unroll
      for (int nh = 0; nh < 2; ++nh)
#pragma unroll
        for (int nt = 0; nt < 2; ++nt) acc[mh][mt][nh][nt] = (fx4)0.0f;

  gemm8<true, 8, 512>(Ag, Bg, lds, acc, wv, lane);

  size_t pbase = (size_t)bh * 1048576;
  float zac[2][2][4];
#pragma unroll
  for (int nh = 0; nh < 2; ++nh)
#pragma unroll
    for (int nt = 0; nt < 2; ++nt)
#pragma unroll
      for (int j = 0; j < 4; ++j) zac[nh][nt][j] = 0.f;
#pragma unroll
  for (int mh = 0; mh < 2; ++mh)
#pragma unroll
    for (int mt = 0; mt < 4; ++mt) {
      int q = q0 + mh * 128 + wr * 64 + mt * 16 + l15;
      size_t qrow = pbase + (size_t)q * 1024;
      int q7 = l15 & 7;
#pragma unroll
      for (int nh = 0; nh < 2; ++nh)
#pragma unroll
        for (int nt = 0; nt < 2; ++nt) {
          int p4 = p0 + nh * 128 + wn * 32 + nt * 16 + kg * 4;
          alignas(8) u16 e4[4];
#pragma unroll
          for (int j = 0; j < 4; ++j) {
            float e = exp2f(acc[mh][mt][nh][nt][j] * KC1);
            zac[nh][nt][j] += e;
            e4[j] = f2bf(e);
          }
          int ch = (p4 >> 3) ^ q7;
          *(u64*)(Pt + qrow + ch * 8 + (p4 & 7)) = *(const u64*)e4;
        }
    }
#pragma unroll
  for (int nh = 0; nh < 2; ++nh)
#pragma unroll
    for (int nt = 0; nt < 2; ++nt)
#pragma unroll
      for (int j = 0; j < 4; ++j) {
        float v = zac[nh][nt][j];
        v += __shfl_xor(v, 1);
        v += __shfl_xor(v, 2);
        v += __shfl_xor(v, 4);
        v += __shfl_xor(v, 8);
        zac[nh][nt][j] = v;
      }
  if (l15 == 0) {
    size_t zb = (size_t)(qt * 2 + wr) * 65536 + (size_t)bh * 1024;
#pragma unroll
    for (int nh = 0; nh < 2; ++nh)
#pragma unroll
      for (int nt = 0; nt < 2; ++nt) {
        int p4 = p0 + nh * 128 + wn * 32 + nt * 16 + kg * 4;
        float4 zv;
        zv.x = zac[nh][nt][0]; zv.y = zac[nh][nt][1];
        zv.z = zac[nh][nt][2]; zv.w = zac[nh][nt][3];
        *(float4*)&Zpart[zb + p4] = zv;
      }
  }
}

__global__ __launch_bounds__(256) void k_zfinal(const float* __restrict__ Zpart,
                                                float* __restrict__ RZ) {
  int idx = blockIdx.x * 256 + threadIdx.x; // 65536
  float s = 0.f;
#pragma unroll
  for (int k = 0; k < 8; ++k) s += Zpart[(size_t)k * 65536 + idx];
  RZ[idx] = 1.0f / s;
}

// ---------------- Vb [p][f] -> Vt [f][p] with 1/Z scale ----------------
__global__ __launch_bounds__(256) void k_vt(const u16* __restrict__ Vb,
                                            const float* __restrict__ RZ,
                                            u16* __restrict__ Vt) {
  __shared__ u16 Vl[64 * 512];
  int bh = blockIdx.x >> 4;
  int ptile = blockIdx.x & 15;
  int tid = threadIdx.x;
  const u16* src = Vb + (size_t)bh * 524288 + (size_t)ptile * 32768;
#pragma unroll
  for (int it = 0; it < 16; ++it) {
    int idx = tid + it * 256;
    int pl = idx >> 6, g = idx & 63;
    float rz = RZ[bh * 1024 + ptile * 64 + pl];
    uint4 v = *(const uint4*)&src[(size_t)pl * 512 + g * 8];
    int cf = g ^ (pl & 7);
    u32 w[4] = {v.x, v.y, v.z, v.w};
    alignas(16) u16 c8v[8];
#pragma unroll
    for (int i = 0; i < 4; ++i) {
      c8v[2 * i]     = f2bf(bf2f((u16)w[i]) * rz);
      c8v[2 * i + 1] = f2bf(bf2f((u16)(w[i] >> 16)) * rz);
    }
    *(uint4*)&Vl[pl * 512 + cf * 8] = *(const uint4*)c8v;
  }
  __syncthreads();
  u16* dst = Vt + (size_t)bh * 524288;
#pragma unroll
  for (int it = 0; it < 16; ++it) {
    int f = (tid & 63) + (it & 7) * 64;
    int pc = (tid >> 6) * 2 + (it >> 3);
    int base = pc * 8 * 512 + f;
    u32 x0 = (u32)Vl[base] | ((u32)Vl[base + 512] << 16);
    u32 x1 = (u32)Vl[base + 1024] | ((u32)Vl[base + 1536] << 16);
    u32 x2 = (u32)Vl[base + 2048] | ((u32)Vl[base + 2560] << 16);
    u32 x3 = (u32)Vl[base + 3072] | ((u32)Vl[base + 3584] << 16);
    uint4 pk; pk.x = x0; pk.y = x1; pk.z = x2; pk.w = x3;
    int col = ptile * 8 + (pc ^ (f & 7));
    *(uint4*)&dst[(size_t)f * 1024 + col * 8] = pk;
  }
}

// ---------------- PV-GEMM -> out (SWAP, float4 stores) ----------------
// grid 512 (bh x 8 tiles), 512 thr, 256x256, NT=16.
// SWAP: col = q = q0+mh*128+wr*64+mt*16+l15, row = f = f0+nh*128+wn*32+nt*16+kg*4+j.
__global__ __launch_bounds__(512) void k_pv(const u16* __restrict__ Pt,
                                            const u16* __restrict__ Vt,
                                            float* __restrict__ out) {
  __shared__ u16 lds[65536];
  int bid = blockIdx.x;
  int vid = (bid & 7) * 64 + (bid >> 3);
  int bh = vid >> 3, tile = vid & 7;
  int q0 = (tile >> 1) * 256, f0 = (tile & 1) * 256;
  int tid = threadIdx.x, lane = tid & 63, wv = tid >> 6;
  int l15 = lane & 15, kg = lane >> 4;
  int wr = wv >> 2, wn = wv & 3;
  const u16* Ag = Pt + (size_t)bh * 1048576 + (size_t)q0 * 1024;
  const u16* Bg = Vt + (size_t)bh * 524288 + (size_t)f0 * 1024;
  fx4 acc[2][4][2][2];
#pragma unroll
  for (int mh = 0; mh < 2; ++mh)
#pragma unroll
    for (int mt = 0; mt < 4; ++mt)
#pragma unroll
      for (int nh = 0; nh < 2; ++nh)
#pragma unroll
        for (int nt = 0; nt < 2; ++nt) acc[mh][mt][nh][nt] = (fx4)0.0f;

  gemm8<true, 16, 1024>(Ag, Bg, lds, acc, wv, lane);

#pragma unroll
  for (int mh = 0; mh < 2; ++mh)
#pragma unroll
    for (int mt = 0; mt < 4; ++mt) {
      int q = q0 + mh * 128 + wr * 64 + mt * 16 + l15;
#pragma unroll
      for (int nh = 0; nh < 2; ++nh)
#pragma unroll
        for (int nt = 0; nt < 2; ++nt) {
          int fb = f0 + nh * 128 + wn * 32 + nt * 16 + kg * 4; // t = kg*4+j
          int d = fb >> 4, t0 = fb & 15;
          float4 v;
          v.x = acc[mh][mt][nh][nt][0];
          v.y = acc[mh][mt][nh][nt][1];
          v.z = acc[mh][mt][nh][nt][2];
          v.w = acc[mh][mt][nh][nt][3];
          *(float4*)&out[(size_t)(bh * 32 + d) * 16384 + (size_t)q * 16 + t0] = v;
        }
    }
}

extern "C" void kernel_launch(void* const* d_in, const int* in_sizes, int n_in,
                              void* d_out, int out_size, void* d_ws, size_t ws_size,
                              hipStream_t stream) {
  (void)in_sizes; (void)n_in; (void)out_size; (void)ws_size;
  const float* x  = (const float*)d_in[0];
  const float* Wk = (const float*)d_in[1];
  const float* Wq = (const float*)d_in[2];
  const float* Wv = (const float*)d_in[3];
  float* out = (float*)d_out;

  u16* Kb  = (u16*)d_ws;                  // [ 0, 64) MiB  [64 bh][1024 p][512 f]
  u16* Qb  = Kb + 33554432;               // [64,128) MiB
  u16* Vb  = Qb + 33554432;               // [128,192) MiB
  u16* Xbf = Vb + 33554432;               // [192,256) MiB [8 b][16384 n][256 c]
  u16* Pt  = Xbf;                         // [192,320) MiB (overlays dead Xbf)
  u16* Vt  = Qb;                          // [64,128) MiB  (overlays dead Qb)
  float* Zpart = (float*)(Kb + 167772160);// 320 MiB: [8][64][1024]
  float* RZ = Zpart + 524288;             // [64][1024]
  u16* Wall = (u16*)(RZ + 65536);         // [768][256]

  k_wconv<<<96, 256, 0, stream>>>(Wk, Wq, Wv, Wall);
  k_xt<<<1024, 256, 0, stream>>>(x, Xbf);
  k_proj2<<<1536, 512, 0, stream>>>(Xbf, Wall, Kb, Qb, Vb);
  k_egemm<<<1024, 512, 0, stream>>>(Qb, Kb, Pt, Zpart);
  k_zfinal<<<256, 256, 0, stream>>>(Zpart, RZ);
  k_vt<<<1024, 256, 0, stream>>>(Vb, RZ, Vt);
  k_pv<<<512, 512, 0, stream>>>(Pt, Vt, out);
}

// Round 12
// 320.849 us; speedup vs baseline: 1.2314x; 1.0859x over previous
//
#include <hip/hip_runtime.h>

// MultiHeadAttention: B=8, C=256, H=8, D=32, T=16, P=1024, F=D*T=512
//  k_wconv : W fp32 -> Wall[768][256] bf16 (chunk-swizzled by o&7)
//  k_xt    : x fp32 [b][c][n] -> Xbf [b][n][c] bf16 (chunk-swizzled by n&7)
//  k_proj2 : GEMM Wall x Xbf. K,Q written as fp8e4m3 x16 [bh][p][512] u8
//            (8-elem-unit swizzle u^=(p&7), 4B stores); V as bf16 (as before).
//  k_egemm : fp8 QK^T (mfma_f32_16x16x32_fp8_fp8, 64 KiB LDS -> 2 blocks/CU)
//            Pt = bf16(exp2(E*KC1/256)) + fused partial Z. SWAP epilogue.
//  k_zfinal: RZ[bh][p] = 1/sum(8 Zpart slices)
//  k_vt    : Vb [p][f] -> Vt [bh][f][1024] bf16 with 1/Z[p] folded in
//  k_pv    : out = Pt x Vt' (bf16 gemm8, SWAP, float4 stores)

typedef unsigned char u8;
typedef unsigned short u16;
typedef unsigned int u32;
typedef unsigned long long u64;
typedef __attribute__((ext_vector_type(8))) short bfx8;
typedef __attribute__((ext_vector_type(4))) float fx4;

constexpr float KC1 = 1.4426950408889634f / 22.627416997969522f; // log2(e)/sqrt(512)
constexpr float KC8 = KC1 / 256.0f;   // fp8 path: K,Q each scaled by 16
constexpr float S8 = 16.0f;

__device__ __forceinline__ u16 f2bf(float f) {
  u32 u = __builtin_bit_cast(u32, f);
  return (u16)((u + 0x7fffu + ((u >> 16) & 1u)) >> 16);
}
__device__ __forceinline__ float bf2f(u16 v) {
  return __builtin_bit_cast(float, (u32)v << 16);
}
__device__ __forceinline__ fx4 mfma16(bfx8 a, bfx8 b, fx4 c) {
  return __builtin_amdgcn_mfma_f32_16x16x32_bf16(a, b, c, 0, 0, 0);
}
__device__ __forceinline__ fx4 mfma8(long a, long b, fx4 c) {
  return __builtin_amdgcn_mfma_f32_16x16x32_fp8_fp8(a, b, c, 0, 0, 0);
}
typedef __attribute__((address_space(1))) const unsigned int* as1p;
typedef __attribute__((address_space(3))) unsigned int* as3p;
__device__ __forceinline__ void gll16(const void* g, void* l) {
  __builtin_amdgcn_global_load_lds((as1p)g, (as3p)l, 16, 0, 0);
}
__device__ __forceinline__ void midbar_() { __builtin_amdgcn_s_barrier(); }
__device__ __forceinline__ void pend_() {
  __builtin_amdgcn_s_barrier();
  __builtin_amdgcn_sched_barrier(0);
}
#define VMC(n) do { asm volatile("s_waitcnt vmcnt(" #n ")" ::: "memory"); \
                    __builtin_amdgcn_sched_barrier(0); } while (0)

// ---- bf16 8-phase 256x256 GEMM core (round-5/11, verified) ----
template <bool SWAP, int NT, int LK>
__device__ __forceinline__ void gemm8(const u16* __restrict__ Ag,
                                      const u16* __restrict__ Bg,
                                      u16* lds, fx4 (&acc)[2][4][2][2],
                                      int wv, int lane) {
  const int l15 = lane & 15, kg = lane >> 4, l7 = lane & 7;
  const int wr = wv >> 2, wn = wv & 3;
  const int rsub = lane >> 3, csub = (lane & 7) * 8;
  constexpr int A0 = 0, A1 = 16384, B0 = 32768, B1 = 49152;
  bfx8 af[4][2], bf[2][2][2];

  auto stg = [&](const u16* g, int ldsoff, int tile, int half) {
    const u16* gp = g + (size_t)(half * 128 + wv * 16 + rsub) * LK + tile * 64 + csub;
    u16* lp = lds + ldsoff + half * 8192 + wv * 1024;
    gll16(gp, lp);
    gll16(gp + (size_t)8 * LK, lp + 512);
  };
  auto LA = [&](int boff, int mh) {
    const u16* base = lds + boff + mh * 8192 + wr * 4096;
#pragma unroll
    for (int mt = 0; mt < 4; ++mt)
#pragma unroll
      for (int kk = 0; kk < 2; ++kk)
        af[mt][kk] = *(const bfx8*)(base + (mt * 16 + l15) * 64 + (((kk << 2) + kg) ^ l7) * 8);
  };
  auto LB = [&](int boff, int nh) {
    const u16* base = lds + boff + nh * 8192 + wn * 2048;
#pragma unroll
    for (int nt = 0; nt < 2; ++nt)
#pragma unroll
      for (int kk = 0; kk < 2; ++kk)
        bf[nh][nt][kk] = *(const bfx8*)(base + (nt * 16 + l15) * 64 + (((kk << 2) + kg) ^ l7) * 8);
  };
  auto MM = [&](int mh, int nh) {
    __builtin_amdgcn_s_setprio(1);
#pragma unroll
    for (int mt = 0; mt < 4; ++mt)
#pragma unroll
      for (int nt = 0; nt < 2; ++nt)
#pragma unroll
        for (int kk = 0; kk < 2; ++kk) {
          if constexpr (SWAP)
            acc[mh][mt][nh][nt] = mfma16(bf[nh][nt][kk], af[mt][kk], acc[mh][mt][nh][nt]);
          else
            acc[mh][mt][nh][nt] = mfma16(af[mt][kk], bf[nh][nt][kk], acc[mh][mt][nh][nt]);
        }
    __builtin_amdgcn_s_setprio(0);
  };

  stg(Ag, A0, 0, 0); stg(Ag, A0, 0, 1);
  stg(Bg, B0, 0, 0); stg(Bg, B0, 0, 1);
  stg(Ag, A1, 1, 0); stg(Bg, B1, 1, 1);
  VMC(4);
  pend_();

  constexpr int NI = NT / 2;
#pragma unroll 1
  for (int i = 0; i < NI; ++i) {
    const int t = 2 * i;
    const bool more = (i + 1 < NI);
    LA(A0, 0); LB(B0, 0);
    stg(Ag, A1, t + 1, 1);
    midbar_(); MM(0, 0); pend_();
    LB(B0, 1);
    stg(Bg, B1, t + 1, 0);
    midbar_(); MM(0, 1); pend_();
    LA(A0, 1);
    if (more) stg(Ag, A0, t + 2, 0);
    midbar_(); MM(1, 1); pend_();
    if (more) stg(Bg, B0, t + 2, 1);
    midbar_(); MM(1, 0);
    if (more) { VMC(4); } else { VMC(0); }
    pend_();
    LA(A1, 0); LB(B1, 0);
    if (more) stg(Ag, A0, t + 2, 1);
    midbar_(); MM(0, 0); pend_();
    LB(B1, 1);
    if (more) stg(Bg, B0, t + 2, 0);
    midbar_(); MM(0, 1); pend_();
    LA(A1, 1);
    if (more) stg(Ag, A1, t + 3, 0);
    midbar_(); MM(1, 1); pend_();
    if (more) stg(Bg, B1, t + 3, 1);
    midbar_(); MM(1, 0);
    if (more) { VMC(4); }
    pend_();
  }
}

// ---- fp8 8-phase 256x256 GEMM core: same skeleton, half-width operands ----
// LDS 64 KiB: A dbuf @0/@16384, B dbuf @32768/@49152 (u8 offsets).
// Tile = [256 rows][64 K-bytes]; 8B-unit swizzle: physical = logical^ (row&7).
// stg = 1 gll16/wave/half. Ledger: keep newest 2 stages -> vmcnt(2).
template <int NT, int LK>
__device__ __forceinline__ void gemm8f(const u8* __restrict__ Ag,
                                       const u8* __restrict__ Bg,
                                       u8* lds, fx4 (&acc)[2][4][2][2],
                                       int wv, int lane) {
  const int l15 = lane & 15, kg = lane >> 4, l7 = lane & 7;
  const int wr = wv >> 2, wn = wv & 3;
  const int rs4 = lane >> 2, c16 = (lane & 3) * 16;
  constexpr int A0 = 0, A1 = 16384, B0 = 32768, B1 = 49152;
  long af[4][2], bf[2][2][2];

  auto stg = [&](const u8* g, int ldsoff, int tile, int half) {
    const u8* gp = g + (size_t)(half * 128 + wv * 16 + rs4) * LK + tile * 64 + c16;
    gll16(gp, lds + ldsoff + half * 8192 + wv * 1024);
  };
  auto LA = [&](int boff, int mh) {
    const u8* base = lds + boff + mh * 8192 + wr * 4096;
#pragma unroll
    for (int mt = 0; mt < 4; ++mt)
#pragma unroll
      for (int kk = 0; kk < 2; ++kk)
        af[mt][kk] = *(const long*)(base + (mt * 16 + l15) * 64 + ((((kk << 2) + kg) ^ l7) << 3));
  };
  auto LB = [&](int boff, int nh) {
    const u8* base = lds + boff + nh * 8192 + wn * 2048;
#pragma unroll
    for (int nt = 0; nt < 2; ++nt)
#pragma unroll
      for (int kk = 0; kk < 2; ++kk)
        bf[nh][nt][kk] = *(const long*)(base + (nt * 16 + l15) * 64 + ((((kk << 2) + kg) ^ l7) << 3));
  };
  auto MM = [&](int mh, int nh) {   // SWAP form only (row <- B-side)
    __builtin_amdgcn_s_setprio(1);
#pragma unroll
    for (int mt = 0; mt < 4; ++mt)
#pragma unroll
      for (int nt = 0; nt < 2; ++nt)
#pragma unroll
        for (int kk = 0; kk < 2; ++kk)
          acc[mh][mt][nh][nt] = mfma8(bf[nh][nt][kk], af[mt][kk], acc[mh][mt][nh][nt]);
    __builtin_amdgcn_s_setprio(0);
  };

  stg(Ag, A0, 0, 0); stg(Ag, A0, 0, 1);
  stg(Bg, B0, 0, 0); stg(Bg, B0, 0, 1);
  stg(Ag, A1, 1, 0); stg(Bg, B1, 1, 1);
  VMC(2);
  pend_();

  constexpr int NI = NT / 2;
#pragma unroll 1
  for (int i = 0; i < NI; ++i) {
    const int t = 2 * i;
    const bool more = (i + 1 < NI);
    LA(A0, 0); LB(B0, 0);
    stg(Ag, A1, t + 1, 1);
    midbar_(); MM(0, 0); pend_();
    LB(B0, 1);
    stg(Bg, B1, t + 1, 0);
    midbar_(); MM(0, 1); pend_();
    LA(A0, 1);
    if (more) stg(Ag, A0, t + 2, 0);
    midbar_(); MM(1, 1); pend_();
    if (more) stg(Bg, B0, t + 2, 1);
    midbar_(); MM(1, 0);
    if (more) { VMC(2); } else { VMC(0); }
    pend_();
    LA(A1, 0); LB(B1, 0);
    if (more) stg(Ag, A0, t + 2, 1);
    midbar_(); MM(0, 0); pend_();
    LB(B1, 1);
    if (more) stg(Bg, B0, t + 2, 0);
    midbar_(); MM(0, 1); pend_();
    LA(A1, 1);
    if (more) stg(Ag, A1, t + 3, 0);
    midbar_(); MM(1, 1); pend_();
    if (more) stg(Bg, B1, t + 3, 1);
    midbar_(); MM(1, 0);
    if (more) { VMC(2); }
    pend_();
  }
}

// ---------------- W fp32 -> Wall bf16 swizzled ----------------
__global__ __launch_bounds__(256) void k_wconv(const float* __restrict__ Wk,
                                               const float* __restrict__ Wq,
                                               const float* __restrict__ Wv,
                                               u16* __restrict__ Wall) {
  int blk = blockIdx.x;          // 96 = 3 proj * 32
  int pr = blk >> 5;
  const float* src = (pr == 0) ? Wk : ((pr == 1) ? Wq : Wv);
  int oc = (blk & 31) * 8 + (threadIdx.x >> 5);
  int Cc = threadIdx.x & 31;
  const float4* s4 = (const float4*)(src + oc * 256 + Cc * 8);
  float4 a = s4[0], b = s4[1];
  alignas(16) u16 t[8] = {f2bf(a.x), f2bf(a.y), f2bf(a.z), f2bf(a.w),
                          f2bf(b.x), f2bf(b.y), f2bf(b.z), f2bf(b.w)};
  int o = pr * 256 + oc;
  int pos = (Cc & ~7) + ((Cc & 7) ^ (o & 7));
  *(uint4*)(Wall + o * 256 + pos * 8) = *(const uint4*)t;
}

// ---------------- x -> Xbf transpose/convert ----------------
__global__ __launch_bounds__(256) void k_xt(const float* __restrict__ x,
                                            u16* __restrict__ Xbf) {
  __shared__ u16 Xs[128 * 256];
  int b = blockIdx.x >> 7;
  int n0 = (blockIdx.x & 127) * 128;
  int tid = threadIdx.x;
  int ng = tid & 31, cgrp = tid >> 5;
  const float* xb = x + (size_t)b * 4194304 + n0 + ng * 4;
#pragma unroll
  for (int it = 0; it < 4; ++it) {
    int Cc = cgrp + it * 8;
    float4 v[8];
#pragma unroll
    for (int i = 0; i < 8; ++i)
      v[i] = *(const float4*)(xb + (size_t)(Cc * 8 + i) * 16384);
#pragma unroll
    for (int j = 0; j < 4; ++j) {
      int n = ng * 4 + j;
      alignas(16) u16 c8v[8];
#pragma unroll
      for (int i = 0; i < 8; ++i) c8v[i] = f2bf(((const float*)&v[i])[j]);
      int pos = (Cc & ~7) + ((Cc & 7) ^ (n & 7));
      *(uint4*)&Xs[n * 256 + pos * 8] = *(const uint4*)c8v;
    }
  }
  __syncthreads();
  u16* xo = Xbf + (size_t)b * 4194304 + (size_t)n0 * 256;
#pragma unroll
  for (int it = 0; it < 16; ++it) {
    int idx = tid + it * 256;
    int n = idx >> 5, chp = idx & 31;
    uint4 v = *(const uint4*)&Xs[n * 256 + chp * 8];
    *(uint4*)&xo[(size_t)n * 256 + chp * 8] = v;
  }
}

// ---------------- fused 3-projection GEMM ----------------
// grid 1536, 512 thr, 256(o) x 256(n), NT=4. SWAP core. K,Q -> fp8 x16; V -> bf16.
__global__ __launch_bounds__(512) void k_proj2(const u16* __restrict__ Xbf,
                                               const u16* __restrict__ Wall,
                                               u8* __restrict__ Kb8, u8* __restrict__ Qb8,
                                               u16* __restrict__ Vb) {
  __shared__ u16 lds[65536];
  int bid = blockIdx.x;
  int vid = (bid & 7) * 192 + (bid >> 3);
  int nidx = vid / 3;
  int otile = vid - nidx * 3;
  int b = nidx >> 6, ntile = nidx & 63;
  int tid = threadIdx.x, lane = tid & 63, wv = tid >> 6;
  int l15 = lane & 15, kg = lane >> 4;
  int wr = wv >> 2, wn = wv & 3;
  const u16* Ag = Wall + otile * 65536;
  const u16* Bg = Xbf + (size_t)b * 4194304 + (size_t)ntile * 65536;
  fx4 acc[2][4][2][2];
#pragma unroll
  for (int mh = 0; mh < 2; ++mh)
#pragma unroll
    for (int mt = 0; mt < 4; ++mt)
#pragma unroll
      for (int nh = 0; nh < 2; ++nh)
#pragma unroll
        for (int nt = 0; nt < 2; ++nt) acc[mh][mt][nh][nt] = (fx4)0.0f;

  gemm8<true, 4, 256>(Ag, Bg, lds, acc, wv, lane);

#pragma unroll
  for (int mh = 0; mh < 2; ++mh)
#pragma unroll
    for (int mt = 0; mt < 4; ++mt) {
      int o = mh * 128 + wr * 64 + mt * 16 + l15;   // A-side: carries l15
      int h = o >> 5;
      int d = o & 31;
      int f0 = d * 16 + kg * 4;                      // t = kg*4 + j
      if (otile < 2) {
        u8* dst = (otile == 0) ? Kb8 : Qb8;
        size_t bhro = (size_t)(b * 8 + h) * 524288;
        int fu = f0 >> 3, flo = f0 & 7;
#pragma unroll
        for (int nh = 0; nh < 2; ++nh)
#pragma unroll
          for (int nt = 0; nt < 2; ++nt) {
            int p = ntile * 16 + nh * 8 + wn * 2 + nt;
            const fx4& a4 = acc[mh][mt][nh][nt];
            u32 w = __builtin_amdgcn_cvt_pk_fp8_f32(a4[0] * S8, a4[1] * S8, 0, false);
            w = __builtin_amdgcn_cvt_pk_fp8_f32(a4[2] * S8, a4[3] * S8, w, true);
            *(u32*)(dst + bhro + (size_t)p * 512 + ((fu ^ (p & 7)) << 3) + flo) = w;
          }
      } else {
        size_t bhro = (size_t)(b * 8 + h) * 524288;
        int f7 = f0 & 7;
        int fc = f0 >> 3;
#pragma unroll
        for (int nh = 0; nh < 2; ++nh)
#pragma unroll
          for (int nt = 0; nt < 2; ++nt) {
            int p = ntile * 16 + nh * 8 + wn * 2 + nt;
            alignas(8) u16 e4[4];
#pragma unroll
            for (int j = 0; j < 4; ++j) e4[j] = f2bf(acc[mh][mt][nh][nt][j]);
            int ch = fc ^ (p & 7);
            *(u64*)(Vb + bhro + (size_t)p * 512 + ch * 8 + f7) = *(const u64*)e4;
          }
      }
    }
}

// ---------------- fp8 E-GEMM + exp2 -> Pt, fused partial Z ----------------
// grid 1024 (bh x 4 qt x 4 pt), 512 thr, 256x256, NT=8, 64 KiB LDS.
// SWAP: row = p = p0+nh*128+wn*32+nt*16+kg*4+j, col = q = q0+mh*128+wr*64+mt*16+l15.
__global__ __launch_bounds__(512) void k_egemm(const u8* __restrict__ Qb8,
                                               const u8* __restrict__ Kb8,
                                               u16* __restrict__ Pt,
                                               float* __restrict__ Zpart) {
  __shared__ u8 lds[65536];
  int bid = blockIdx.x;
  int vid = (bid & 7) * 128 + (bid >> 3);
  int bh = vid >> 4, qt = (vid >> 2) & 3, pt = vid & 3;
  int q0 = qt * 256, p0 = pt * 256;
  int tid = threadIdx.x, lane = tid & 63, wv = tid >> 6;
  int l15 = lane & 15, kg = lane >> 4;
  int wr = wv >> 2, wn = wv & 3;
  const u8* Ag = Qb8 + (size_t)bh * 524288 + (size_t)q0 * 512;
  const u8* Bg = Kb8 + (size_t)bh * 524288 + (size_t)p0 * 512;
  fx4 acc[2][4][2][2];
#pragma unroll
  for (int mh = 0; mh < 2; ++mh)
#pragma unroll
    for (int mt = 0; mt < 4; ++mt)
#pragma unroll
      for (int nh = 0; nh < 2; ++nh)
#pragma unroll
        for (int nt = 0; nt < 2; ++nt) acc[mh][mt][nh][nt] = (fx4)0.0f;

  gemm8f<8, 512>(Ag, Bg, lds, acc, wv, lane);

  size_t pbase = (size_t)bh * 1048576;
  float zac[2][2][4];
#pragma unroll
  for (int nh = 0; nh < 2; ++nh)
#pragma unroll
    for (int nt = 0; nt < 2; ++nt)
#pragma unroll
      for (int j = 0; j < 4; ++j) zac[nh][nt][j] = 0.f;
#pragma unroll
  for (int mh = 0; mh < 2; ++mh)
#pragma unroll
    for (int mt = 0; mt < 4; ++mt) {
      int q = q0 + mh * 128 + wr * 64 + mt * 16 + l15;
      size_t qrow = pbase + (size_t)q * 1024;
      int q7 = l15 & 7;
#pragma unroll
      for (int nh = 0; nh < 2; ++nh)
#pragma unroll
        for (int nt = 0; nt < 2; ++nt) {
          int p4 = p0 + nh * 128 + wn * 32 + nt * 16 + kg * 4;
          alignas(8) u16 e4[4];
#pragma unroll
          for (int j = 0; j < 4; ++j) {
            float e = exp2f(acc[mh][mt][nh][nt][j] * KC8);
            zac[nh][nt][j] += e;
            e4[j] = f2bf(e);
          }
          int ch = (p4 >> 3) ^ q7;
          *(u64*)(Pt + qrow + ch * 8 + (p4 & 7)) = *(const u64*)e4;
        }
    }
#pragma unroll
  for (int nh = 0; nh < 2; ++nh)
#pragma unroll
    for (int nt = 0; nt < 2; ++nt)
#pragma unroll
      for (int j = 0; j < 4; ++j) {
        float v = zac[nh][nt][j];
        v += __shfl_xor(v, 1);
        v += __shfl_xor(v, 2);
        v += __shfl_xor(v, 4);
        v += __shfl_xor(v, 8);
        zac[nh][nt][j] = v;
      }
  if (l15 == 0) {
    size_t zb = (size_t)(qt * 2 + wr) * 65536 + (size_t)bh * 1024;
#pragma unroll
    for (int nh = 0; nh < 2; ++nh)
#pragma unroll
      for (int nt = 0; nt < 2; ++nt) {
        int p4 = p0 + nh * 128 + wn * 32 + nt * 16 + kg * 4;
        float4 zv;
        zv.x = zac[nh][nt][0]; zv.y = zac[nh][nt][1];
        zv.z = zac[nh][nt][2]; zv.w = zac[nh][nt][3];
        *(float4*)&Zpart[zb + p4] = zv;
      }
  }
}

__global__ __launch_bounds__(256) void k_zfinal(const float* __restrict__ Zpart,
                                                float* __restrict__ RZ) {
  int idx = blockIdx.x * 256 + threadIdx.x; // 65536
  float s = 0.f;
#pragma unroll
  for (int k = 0; k < 8; ++k) s += Zpart[(size_t)k * 65536 + idx];
  RZ[idx] = 1.0f / s;
}

// ---------------- Vb [p][f] -> Vt [f][p] with 1/Z scale ----------------
__global__ __launch_bounds__(256) void k_vt(const u16* __restrict__ Vb,
                                            const float* __restrict__ RZ,
                                            u16* __restrict__ Vt) {
  __shared__ u16 Vl[64 * 512];
  int bh = blockIdx.x >> 4;
  int ptile = blockIdx.x & 15;
  int tid = threadIdx.x;
  const u16* src = Vb + (size_t)bh * 524288 + (size_t)ptile * 32768;
#pragma unroll
  for (int it = 0; it < 16; ++it) {
    int idx = tid + it * 256;
    int pl = idx >> 6, g = idx & 63;
    float rz = RZ[bh * 1024 + ptile * 64 + pl];
    uint4 v = *(const uint4*)&src[(size_t)pl * 512 + g * 8];
    int cf = g ^ (pl & 7);
    u32 w[4] = {v.x, v.y, v.z, v.w};
    alignas(16) u16 c8v[8];
#pragma unroll
    for (int i = 0; i < 4; ++i) {
      c8v[2 * i]     = f2bf(bf2f((u16)w[i]) * rz);
      c8v[2 * i + 1] = f2bf(bf2f((u16)(w[i] >> 16)) * rz);
    }
    *(uint4*)&Vl[pl * 512 + cf * 8] = *(const uint4*)c8v;
  }
  __syncthreads();
  u16* dst = Vt + (size_t)bh * 524288;
#pragma unroll
  for (int it = 0; it < 16; ++it) {
    int f = (tid & 63) + (it & 7) * 64;
    int pc = (tid >> 6) * 2 + (it >> 3);
    int base = pc * 8 * 512 + f;
    u32 x0 = (u32)Vl[base] | ((u32)Vl[base + 512] << 16);
    u32 x1 = (u32)Vl[base + 1024] | ((u32)Vl[base + 1536] << 16);
    u32 x2 = (u32)Vl[base + 2048] | ((u32)Vl[base + 2560] << 16);
    u32 x3 = (u32)Vl[base + 3072] | ((u32)Vl[base + 3584] << 16);
    uint4 pk; pk.x = x0; pk.y = x1; pk.z = x2; pk.w = x3;
    int col = ptile * 8 + (pc ^ (f & 7));
    *(uint4*)&dst[(size_t)f * 1024 + col * 8] = pk;
  }
}

// ---------------- PV-GEMM -> out (bf16, SWAP, float4 stores) ----------------
__global__ __launch_bounds__(512) void k_pv(const u16* __restrict__ Pt,
                                            const u16* __restrict__ Vt,
                                            float* __restrict__ out) {
  __shared__ u16 lds[65536];
  int bid = blockIdx.x;
  int vid = (bid & 7) * 64 + (bid >> 3);
  int bh = vid >> 3, tile = vid & 7;
  int q0 = (tile >> 1) * 256, f0 = (tile & 1) * 256;
  int tid = threadIdx.x, lane = tid & 63, wv = tid >> 6;
  int l15 = lane & 15, kg = lane >> 4;
  int wr = wv >> 2, wn = wv & 3;
  const u16* Ag = Pt + (size_t)bh * 1048576 + (size_t)q0 * 1024;
  const u16* Bg = Vt + (size_t)bh * 524288 + (size_t)f0 * 1024;
  fx4 acc[2][4][2][2];
#pragma unroll
  for (int mh = 0; mh < 2; ++mh)
#pragma unroll
    for (int mt = 0; mt < 4; ++mt)
#pragma unroll
      for (int nh = 0; nh < 2; ++nh)
#pragma unroll
        for (int nt = 0; nt < 2; ++nt) acc[mh][mt][nh][nt] = (fx4)0.0f;

  gemm8<true, 16, 1024>(Ag, Bg, lds, acc, wv, lane);

#pragma unroll
  for (int mh = 0; mh < 2; ++mh)
#pragma unroll
    for (int mt = 0; mt < 4; ++mt) {
      int q = q0 + mh * 128 + wr * 64 + mt * 16 + l15;
#pragma unroll
      for (int nh = 0; nh < 2; ++nh)
#pragma unroll
        for (int nt = 0; nt < 2; ++nt) {
          int fb = f0 + nh * 128 + wn * 32 + nt * 16 + kg * 4; // t = kg*4+j
          int d = fb >> 4, t0 = fb & 15;
          float4 v;
          v.x = acc[mh][mt][nh][nt][0];
          v.y = acc[mh][mt][nh][nt][1];
          v.z = acc[mh][mt][nh][nt][2];
          v.w = acc[mh][mt][nh][nt][3];
          *(float4*)&out[(size_t)(bh * 32 + d) * 16384 + (size_t)q * 16 + t0] = v;
        }
    }
}

extern "C" void kernel_launch(void* const* d_in, const int* in_sizes, int n_in,
                              void* d_out, int out_size, void* d_ws, size_t ws_size,
                              hipStream_t stream) {
  (void)in_sizes; (void)n_in; (void)out_size; (void)ws_size;
  const float* x  = (const float*)d_in[0];
  const float* Wk = (const float*)d_in[1];
  const float* Wq = (const float*)d_in[2];
  const float* Wv = (const float*)d_in[3];
  float* out = (float*)d_out;

  u8* base = (u8*)d_ws;
  u8*  Kb8 = base;                          // [  0, 32) MiB [64 bh][1024 p][512] u8
  u8*  Qb8 = base + 33554432;               // [ 32, 64)
  u16* Vb  = (u16*)(base + 67108864);       // [ 64,128) MiB bf16 [bh][p][512]
  u16* Xbf = (u16*)(base + 134217728);      // [128,192) MiB bf16 [b][n][c]
  u16* Pt  = Xbf;                           // [128,256) MiB (overlays dead Xbf)
  u16* Vt  = (u16*)(base + 268435456);      // [256,320) MiB bf16 [bh][f][1024]
  float* Zpart = (float*)(base + 335544320);// [8][64][1024]
  float* RZ = Zpart + 524288;               // [64][1024]
  u16* Wall = (u16*)(RZ + 65536);           // [768][256]

  k_wconv<<<96, 256, 0, stream>>>(Wk, Wq, Wv, Wall);
  k_xt<<<1024, 256, 0, stream>>>(x, Xbf);
  k_proj2<<<1536, 512, 0, stream>>>(Xbf, Wall, Kb8, Qb8, Vb);
  k_egemm<<<1024, 512, 0, stream>>>(Qb8, Kb8, Pt, Zpart);
  k_zfinal<<<256, 256, 0, stream>>>(Zpart, RZ);
  k_vt<<<1024, 256, 0, stream>>>(Vb, RZ, Vt);
  k_pv<<<512, 512, 0, stream>>>(Pt, Vt, out);
}